// Round 1
// baseline (463.232 us; speedup 1.0000x reference)
//
#include <hip/hip_runtime.h>

// Problem constants (fixed shapes)
#define SEQ   2048
#define NB    2
#define NHQ   32
#define NHKV  8
#define HD    128
#define QTILE 256      // q rows per block
#define KVB   64       // kv rows per tile
#define NWAVE 8
#define KPAD  136      // K_lds row stride in shorts (272B, 16B aligned, bank step 4)
#define VPAD  72       // Vt_lds row stride in shorts (144B, 16B aligned, bank step 4)
#define PPAD  72       // P_lds row stride in shorts
#define SCALE 0.08838834764831845f  // 1/sqrt(128)

#define QSTRIDE (NB * NHQ * HD)    // 8192 floats per q row
#define KSTRIDE (NB * NHKV * HD)   // 2048 floats per kv row

typedef float f32x4 __attribute__((ext_vector_type(4)));
typedef __bf16 bf16x8 __attribute__((ext_vector_type(8)));
typedef unsigned short ushort8 __attribute__((ext_vector_type(8)));

__device__ __forceinline__ unsigned short f2bf(float f) {
    union { float f; unsigned u; } c; c.f = f;
    return (unsigned short)((c.u + 0x7fffu + ((c.u >> 16) & 1u)) >> 16);
}

__global__ __launch_bounds__(512, 2)
void attn_fwd(const float* __restrict__ Q, const float* __restrict__ K,
              const float* __restrict__ V, float* __restrict__ O) {
    __shared__ __align__(16) unsigned short kbuf[KVB * KPAD];       // [kv][d] padded
    __shared__ __align__(16) unsigned short vbuf[HD * VPAD];        // [d][kv] padded (V transposed)
    __shared__ __align__(16) unsigned short pbuf[NWAVE][16 * PPAD]; // per-wave P tile

    const int tid   = threadIdx.x;
    const int w     = tid >> 6;
    const int lane  = tid & 63;
    const int row16 = lane & 15;   // MFMA row/col within 16
    const int kg    = lane >> 4;   // k-group 0..3

    const int bid   = blockIdx.x;
    const int qtile = bid & 7;
    const int g     = (bid >> 3) & 3;
    const int b     = (bid >> 5) & 1;
    const int hkv   = bid >> 6;
    const int hq    = hkv * 4 + g;

    const int qbase = qtile * QTILE + w * 32;

    // ---- Q fragments in registers (scaled, bf16). A-layout: row=lane&15, k=8*(lane>>4)+j ----
    ushort8 qf[2][4];
#pragma unroll
    for (int s = 0; s < 2; ++s) {
        const int qrow = qbase + s * 16 + row16;
        const float* qp = Q + (size_t)qrow * QSTRIDE + b * (NHQ * HD) + hq * HD;
#pragma unroll
        for (int kk = 0; kk < 4; ++kk) {
            const float* p = qp + kk * 32 + kg * 8;
            float4 f0 = *(const float4*)(p);
            float4 f1 = *(const float4*)(p + 4);
            ushort8 u;
            u[0] = f2bf(f0.x * SCALE); u[1] = f2bf(f0.y * SCALE);
            u[2] = f2bf(f0.z * SCALE); u[3] = f2bf(f0.w * SCALE);
            u[4] = f2bf(f1.x * SCALE); u[5] = f2bf(f1.y * SCALE);
            u[6] = f2bf(f1.z * SCALE); u[7] = f2bf(f1.w * SCALE);
            qf[s][kk] = u;
        }
    }

    // ---- online softmax state + output accumulators ----
    float m[2][4], lsum[2][4];
    f32x4 acco[2][8];
#pragma unroll
    for (int s = 0; s < 2; ++s)
#pragma unroll
        for (int r = 0; r < 4; ++r) { m[s][r] = -1e30f; lsum[s][r] = 0.f; }
#pragma unroll
    for (int s = 0; s < 2; ++s)
#pragma unroll
        for (int n = 0; n < 8; ++n) acco[s][n] = (f32x4)0.f;

    const float* kb0 = K + b * (NHKV * HD) + hkv * HD;
    const float* vb0 = V + b * (NHKV * HD) + hkv * HD;

    for (int kvt = 0; kvt < SEQ / KVB; ++kvt) {
        const int kv0 = kvt * KVB;
        __syncthreads();   // protect LDS from previous iteration's readers

        // ---- stage K tile: [64][128] fp32 -> bf16, row-major padded ----
        const float* kb = kb0 + (size_t)kv0 * KSTRIDE;
#pragma unroll
        for (int i = 0; i < 2; ++i) {
            int c = i * 512 + tid;
            int row = c >> 4, c8 = c & 15;
            const float* src = kb + (size_t)row * KSTRIDE + c8 * 8;
            float4 f0 = *(const float4*)(src);
            float4 f1 = *(const float4*)(src + 4);
            ushort8 u;
            u[0] = f2bf(f0.x); u[1] = f2bf(f0.y); u[2] = f2bf(f0.z); u[3] = f2bf(f0.w);
            u[4] = f2bf(f1.x); u[5] = f2bf(f1.y); u[6] = f2bf(f1.z); u[7] = f2bf(f1.w);
            *(ushort8*)&kbuf[row * KPAD + c8 * 8] = u;
        }
        // ---- stage V tile transposed: vbuf[d][kv] ----
        const float* vb = vb0 + (size_t)kv0 * KSTRIDE;
#pragma unroll
        for (int i = 0; i < 4; ++i) {
            int f4i = i * 512 + tid;
            int kv = f4i >> 5, d0 = (f4i & 31) * 4;
            float4 v4 = *(const float4*)(vb + (size_t)kv * KSTRIDE + d0);
            vbuf[(d0 + 0) * VPAD + kv] = f2bf(v4.x);
            vbuf[(d0 + 1) * VPAD + kv] = f2bf(v4.y);
            vbuf[(d0 + 2) * VPAD + kv] = f2bf(v4.z);
            vbuf[(d0 + 3) * VPAD + kv] = f2bf(v4.w);
        }
        __syncthreads();

        // ---- S = Q K^T for both strips (share K fragments) ----
        f32x4 sa[2][4];
#pragma unroll
        for (int s = 0; s < 2; ++s)
#pragma unroll
            for (int n = 0; n < 4; ++n) sa[s][n] = (f32x4)0.f;
#pragma unroll
        for (int kk = 0; kk < 4; ++kk) {
#pragma unroll
            for (int n = 0; n < 4; ++n) {
                bf16x8 bfr = *(const bf16x8*)&kbuf[(n * 16 + row16) * KPAD + kk * 32 + kg * 8];
                sa[0][n] = __builtin_amdgcn_mfma_f32_16x16x32_bf16(
                    __builtin_bit_cast(bf16x8, qf[0][kk]), bfr, sa[0][n], 0, 0, 0);
                sa[1][n] = __builtin_amdgcn_mfma_f32_16x16x32_bf16(
                    __builtin_bit_cast(bf16x8, qf[1][kk]), bfr, sa[1][n], 0, 0, 0);
            }
        }

        // ---- per strip: online softmax + PV ----
#pragma unroll
        for (int s = 0; s < 2; ++s) {
#pragma unroll
            for (int r = 0; r < 4; ++r) {
                // tile row max over 64 kv (4 nblocks in-lane, then 16 lanes)
                float tm = fmaxf(fmaxf(sa[s][0][r], sa[s][1][r]), fmaxf(sa[s][2][r], sa[s][3][r]));
                tm = fmaxf(tm, __shfl_xor(tm, 1, 16));
                tm = fmaxf(tm, __shfl_xor(tm, 2, 16));
                tm = fmaxf(tm, __shfl_xor(tm, 4, 16));
                tm = fmaxf(tm, __shfl_xor(tm, 8, 16));
                float mn   = fmaxf(m[s][r], tm);
                float corr = __expf(m[s][r] - mn);
                float ps = 0.f;
                int prow = kg * 4 + r;   // C-layout row of this reg
#pragma unroll
                for (int n = 0; n < 4; ++n) {
                    float p = __expf(sa[s][n][r] - mn);
                    ps += p;
                    pbuf[w][prow * PPAD + n * 16 + row16] = f2bf(p);
                }
                ps += __shfl_xor(ps, 1, 16);
                ps += __shfl_xor(ps, 2, 16);
                ps += __shfl_xor(ps, 4, 16);
                ps += __shfl_xor(ps, 8, 16);
                lsum[s][r] = lsum[s][r] * corr + ps;
                m[s][r] = mn;
#pragma unroll
                for (int n8 = 0; n8 < 8; ++n8) acco[s][n8][r] *= corr;
            }
            // PV: O[16x128] += P[16x64] * V[64x128]
#pragma unroll
            for (int kk2 = 0; kk2 < 2; ++kk2) {
                bf16x8 pa = *(const bf16x8*)&pbuf[w][row16 * PPAD + kk2 * 32 + kg * 8];
#pragma unroll
                for (int n8 = 0; n8 < 8; ++n8) {
                    bf16x8 vf = *(const bf16x8*)&vbuf[(n8 * 16 + row16) * VPAD + kk2 * 32 + kg * 8];
                    acco[s][n8] = __builtin_amdgcn_mfma_f32_16x16x32_bf16(pa, vf, acco[s][n8], 0, 0, 0);
                }
            }
        }
    }

    // ---- epilogue: normalize and store fp32 ----
    float* ob = O + b * (NHQ * HD) + hq * HD;
#pragma unroll
    for (int s = 0; s < 2; ++s)
#pragma unroll
        for (int r = 0; r < 4; ++r) {
            float inv = 1.f / lsum[s][r];
            int qrow = qbase + s * 16 + kg * 4 + r;
            float* op = ob + (size_t)qrow * QSTRIDE;
#pragma unroll
            for (int n8 = 0; n8 < 8; ++n8)
                op[n8 * 16 + row16] = acco[s][n8][r] * inv;
        }
}

extern "C" void kernel_launch(void* const* d_in, const int* in_sizes, int n_in,
                              void* d_out, int out_size, void* d_ws, size_t ws_size,
                              hipStream_t stream) {
    (void)in_sizes; (void)n_in; (void)ws_size; (void)d_ws; (void)out_size;
    const float* Q = (const float*)d_in[0];
    const float* K = (const float*)d_in[1];
    const float* V = (const float*)d_in[2];
    float* Out = (float*)d_out;
    // grid: 8 qtiles * 4 groups * 2 batch * 8 kv-heads = 512 blocks
    dim3 grid(512), block(512);
    attn_fwd<<<grid, block, 0, stream>>>(Q, K, V, Out);
}

// Round 2
// 269.603 us; speedup vs baseline: 1.7182x; 1.7182x over previous
//
#include <hip/hip_runtime.h>

// Shapes (fixed)
#define SEQ   2048
#define NB    2
#define NHQ   32
#define NHKV  8
#define HD    128
#define QTILE 256
#define KVB   64
#define NWAVE 8
#define PPAD  72
#define SCALE 0.08838834764831845f

#define QSTRIDE (NB * NHQ * HD)    // 8192
#define KSTRIDE (NB * NHKV * HD)   // 2048

typedef float f32x4 __attribute__((ext_vector_type(4)));
typedef __bf16 bf16x8 __attribute__((ext_vector_type(8)));
typedef unsigned short ushort8 __attribute__((ext_vector_type(8)));
typedef unsigned int u32;

__device__ __forceinline__ unsigned short f2bf(float f) {
    union { float f; unsigned u; } c; c.f = f;
    return (unsigned short)((c.u + 0x7fffu + ((c.u >> 16) & 1u)) >> 16);
}

__device__ __forceinline__ void gload_lds16(const unsigned short* g, unsigned short* l) {
    __builtin_amdgcn_global_load_lds((const __attribute__((address_space(1))) u32*)g,
                                     (__attribute__((address_space(3))) u32*)l, 16, 0, 0);
}

// ---------------- pre-pass 1: K -> bf16, XOR-swizzled 16B chunks ----------------
// Kws[bh][s][chunk c] = bf16(K[s][bh][chunk c ^ (s&7)])
__global__ __launch_bounds__(256) void conv_k(const float* __restrict__ K,
                                              unsigned short* __restrict__ Kws) {
    int idx = blockIdx.x * 256 + threadIdx.x;      // one 16B out chunk each
    int c  = idx & 15;
    int s  = (idx >> 4) & 2047;
    int bh = idx >> 15;                            // b*8+h
    int cs = c ^ (s & 7);
    const float* src = K + ((size_t)s * 16 + bh) * 128 + cs * 8;
    float4 f0 = *(const float4*)src;
    float4 f1 = *(const float4*)(src + 4);
    ushort8 u;
    u[0] = f2bf(f0.x); u[1] = f2bf(f0.y); u[2] = f2bf(f0.z); u[3] = f2bf(f0.w);
    u[4] = f2bf(f1.x); u[5] = f2bf(f1.y); u[6] = f2bf(f1.z); u[7] = f2bf(f1.w);
    *(ushort8*)&Kws[((size_t)bh * 2048 + s) * 128 + c * 8] = u;
}

// ---------------- pre-pass 2: V -> bf16 transposed [bh][d][seq], swizzled ----------------
// Vt[bh][d][t64*64 + c*8 + e] = bf16(V[t64*64 + (c^(d&7))*8 + e][bh][d])
__global__ __launch_bounds__(256) void conv_v(const float* __restrict__ V,
                                              unsigned short* __restrict__ Vt) {
    __shared__ float tile[64][129];
    int t64 = blockIdx.x & 31;
    int bh  = blockIdx.x >> 5;
    int kv0 = t64 * 64;
#pragma unroll
    for (int i = 0; i < 8; ++i) {
        int f4 = i * 256 + threadIdx.x;            // 0..2047
        int kv = f4 >> 5, d4 = (f4 & 31) * 4;
        float4 v = *(const float4*)(V + ((size_t)(kv0 + kv) * 16 + bh) * 128 + d4);
        tile[kv][d4] = v.x; tile[kv][d4 + 1] = v.y;
        tile[kv][d4 + 2] = v.z; tile[kv][d4 + 3] = v.w;
    }
    __syncthreads();
#pragma unroll
    for (int i = 0; i < 4; ++i) {
        int lin = i * 256 + threadIdx.x;           // 0..1023
        int c = lin & 7, d = lin >> 3;
        int cs = c ^ (d & 7);
        ushort8 u;
#pragma unroll
        for (int j = 0; j < 8; ++j) u[j] = f2bf(tile[cs * 8 + j][d]);
        *(ushort8*)&Vt[((size_t)bh * 128 + d) * 2048 + kv0 + c * 8] = u;
    }
}

// ---------------- main attention kernel ----------------
__global__ __launch_bounds__(512, 2)
void attn_fwd2(const float* __restrict__ Q, const unsigned short* __restrict__ Kws,
               const unsigned short* __restrict__ Vtws, float* __restrict__ O) {
    __shared__ __align__(16) unsigned short kbuf[2][KVB * 128];   // 32 KB (rows 256B, swizzled)
    __shared__ __align__(16) unsigned short vbuf[2][HD * 64];     // 32 KB (rows 128B, swizzled)
    __shared__ __align__(16) unsigned short pbuf[NWAVE][2][16 * PPAD]; // 36.9 KB

    const int tid   = threadIdx.x;
    const int w     = tid >> 6;
    const int lane  = tid & 63;
    const int row16 = lane & 15;
    const int kg    = lane >> 4;

    const int bid   = blockIdx.x;
    const int qtile = bid & 7;
    const int g     = (bid >> 3) & 3;
    const int b     = (bid >> 5) & 1;
    const int hkv   = bid >> 6;
    const int hq    = hkv * 4 + g;

    const int qbase = qtile * QTILE + w * 32;

    // Q fragments (fp32 -> scaled bf16), A-layout: row=lane&15, k=8*kg+j
    ushort8 qf[2][4];
#pragma unroll
    for (int s = 0; s < 2; ++s) {
        const int qrow = qbase + s * 16 + row16;
        const float* qp = Q + (size_t)qrow * QSTRIDE + b * (NHQ * HD) + hq * HD;
#pragma unroll
        for (int kk = 0; kk < 4; ++kk) {
            const float* p = qp + kk * 32 + kg * 8;
            float4 f0 = *(const float4*)(p);
            float4 f1 = *(const float4*)(p + 4);
            ushort8 u;
            u[0] = f2bf(f0.x * SCALE); u[1] = f2bf(f0.y * SCALE);
            u[2] = f2bf(f0.z * SCALE); u[3] = f2bf(f0.w * SCALE);
            u[4] = f2bf(f1.x * SCALE); u[5] = f2bf(f1.y * SCALE);
            u[6] = f2bf(f1.z * SCALE); u[7] = f2bf(f1.w * SCALE);
            qf[s][kk] = u;
        }
    }

    float m[2][4], lsum[2][4];
    f32x4 acco[2][8];
#pragma unroll
    for (int s = 0; s < 2; ++s)
#pragma unroll
        for (int r = 0; r < 4; ++r) { m[s][r] = -1e30f; lsum[s][r] = 0.f; }
#pragma unroll
    for (int s = 0; s < 2; ++s)
#pragma unroll
        for (int n = 0; n < 8; ++n) acco[s][n] = (f32x4)0.f;

    const unsigned short* kbh = Kws + (size_t)(b * 8 + hkv) * 2048 * 128;
    const unsigned short* vbh = Vtws + (size_t)(b * 8 + hkv) * 128 * 2048;

    // wave w stages K chunks {2w,2w+1} and Vt chunks {2w,2w+1} (1 KB each)
#define STAGE(bufi, tt) do {                                                          \
        const int kv0s = (tt) * KVB;                                                  \
        _Pragma("unroll")                                                             \
        for (int i_ = 0; i_ < 2; ++i_) {                                              \
            const int c_ = w * 2 + i_;                                                \
            gload_lds16(kbh + (size_t)(kv0s + c_ * 4 + (lane >> 4)) * 128 + (lane & 15) * 8, \
                        &kbuf[bufi][c_ * 512]);                                       \
            gload_lds16(vbh + (size_t)(c_ * 8 + (lane >> 3)) * 2048 + kv0s + (lane & 7) * 8, \
                        &vbuf[bufi][c_ * 512]);                                       \
        }                                                                             \
    } while (0)

    STAGE(0, 0);
    int cur = 0;

    for (int t = 0; t < SEQ / KVB; ++t) {
        __syncthreads();                 // drains vmcnt: buf[cur] ready; prev readers done
        if (t + 1 < SEQ / KVB) STAGE(cur ^ 1, t + 1);

        // ---- QK^T (K fragments shared across both strips) ----
        f32x4 sa[2][4];
#pragma unroll
        for (int s = 0; s < 2; ++s)
#pragma unroll
            for (int n = 0; n < 4; ++n) sa[s][n] = (f32x4)0.f;
#pragma unroll
        for (int kk = 0; kk < 4; ++kk) {
#pragma unroll
            for (int n = 0; n < 4; ++n) {
                const int r = n * 16 + row16;
                bf16x8 bfr = *(const bf16x8*)&kbuf[cur][r * 128 + (((kk * 4 + kg) ^ (r & 7)) * 8)];
                sa[0][n] = __builtin_amdgcn_mfma_f32_16x16x32_bf16(
                    __builtin_bit_cast(bf16x8, qf[0][kk]), bfr, sa[0][n], 0, 0, 0);
                sa[1][n] = __builtin_amdgcn_mfma_f32_16x16x32_bf16(
                    __builtin_bit_cast(bf16x8, qf[1][kk]), bfr, sa[1][n], 0, 0, 0);
            }
        }

        // ---- online softmax (both strips) -> pbuf ----
#pragma unroll
        for (int s = 0; s < 2; ++s) {
#pragma unroll
            for (int r = 0; r < 4; ++r) {
                float tm = fmaxf(fmaxf(sa[s][0][r], sa[s][1][r]), fmaxf(sa[s][2][r], sa[s][3][r]));
                tm = fmaxf(tm, __shfl_xor(tm, 1, 16));
                tm = fmaxf(tm, __shfl_xor(tm, 2, 16));
                tm = fmaxf(tm, __shfl_xor(tm, 4, 16));
                tm = fmaxf(tm, __shfl_xor(tm, 8, 16));
                float mn   = fmaxf(m[s][r], tm);
                float corr = __expf(m[s][r] - mn);
                float ps = 0.f;
                const int prow = kg * 4 + r;
#pragma unroll
                for (int n = 0; n < 4; ++n) {
                    float p = __expf(sa[s][n][r] - mn);
                    ps += p;
                    pbuf[w][s][prow * PPAD + n * 16 + row16] = f2bf(p);
                }
                ps += __shfl_xor(ps, 1, 16);
                ps += __shfl_xor(ps, 2, 16);
                ps += __shfl_xor(ps, 4, 16);
                ps += __shfl_xor(ps, 8, 16);
                lsum[s][r] = lsum[s][r] * corr + ps;
                m[s][r] = mn;
#pragma unroll
                for (int n8 = 0; n8 < 8; ++n8) acco[s][n8][r] *= corr;
            }
        }

        // ---- PV: V fragments shared across both strips ----
#pragma unroll
        for (int kk2 = 0; kk2 < 2; ++kk2) {
            bf16x8 pa0 = *(const bf16x8*)&pbuf[w][0][row16 * PPAD + kk2 * 32 + kg * 8];
            bf16x8 pa1 = *(const bf16x8*)&pbuf[w][1][row16 * PPAD + kk2 * 32 + kg * 8];
#pragma unroll
            for (int n8 = 0; n8 < 8; ++n8) {
                const int d = n8 * 16 + row16;
                bf16x8 vf = *(const bf16x8*)&vbuf[cur][d * 64 + (((kk2 * 4 + kg) ^ (d & 7)) * 8)];
                acco[0][n8] = __builtin_amdgcn_mfma_f32_16x16x32_bf16(pa0, vf, acco[0][n8], 0, 0, 0);
                acco[1][n8] = __builtin_amdgcn_mfma_f32_16x16x32_bf16(pa1, vf, acco[1][n8], 0, 0, 0);
            }
        }
        cur ^= 1;
    }
#undef STAGE

    // ---- epilogue ----
    float* ob = O + b * (NHQ * HD) + hq * HD;
#pragma unroll
    for (int s = 0; s < 2; ++s)
#pragma unroll
        for (int r = 0; r < 4; ++r) {
            float inv = 1.f / lsum[s][r];
            int qrow = qbase + s * 16 + kg * 4 + r;
            float* op = ob + (size_t)qrow * QSTRIDE;
#pragma unroll
            for (int n8 = 0; n8 < 8; ++n8)
                op[n8 * 16 + row16] = acco[s][n8][r] * inv;
        }
}

// ---------------- fallback (round-1 kernel, used if ws too small) ----------------
#define KPAD  136
#define VPAD  72
__global__ __launch_bounds__(512, 2)
void attn_fwd(const float* __restrict__ Q, const float* __restrict__ K,
              const float* __restrict__ V, float* __restrict__ O) {
    __shared__ __align__(16) unsigned short kbuf[KVB * KPAD];
    __shared__ __align__(16) unsigned short vbuf[HD * VPAD];
    __shared__ __align__(16) unsigned short pbuf[NWAVE][16 * PPAD];

    const int tid = threadIdx.x;
    const int w = tid >> 6, lane = tid & 63;
    const int row16 = lane & 15, kg = lane >> 4;
    const int bid = blockIdx.x;
    const int qtile = bid & 7, g = (bid >> 3) & 3, b = (bid >> 5) & 1, hkv = bid >> 6;
    const int hq = hkv * 4 + g;
    const int qbase = qtile * QTILE + w * 32;

    ushort8 qf[2][4];
#pragma unroll
    for (int s = 0; s < 2; ++s) {
        const int qrow = qbase + s * 16 + row16;
        const float* qp = Q + (size_t)qrow * QSTRIDE + b * (NHQ * HD) + hq * HD;
#pragma unroll
        for (int kk = 0; kk < 4; ++kk) {
            const float* p = qp + kk * 32 + kg * 8;
            float4 f0 = *(const float4*)(p);
            float4 f1 = *(const float4*)(p + 4);
            ushort8 u;
            u[0] = f2bf(f0.x * SCALE); u[1] = f2bf(f0.y * SCALE);
            u[2] = f2bf(f0.z * SCALE); u[3] = f2bf(f0.w * SCALE);
            u[4] = f2bf(f1.x * SCALE); u[5] = f2bf(f1.y * SCALE);
            u[6] = f2bf(f1.z * SCALE); u[7] = f2bf(f1.w * SCALE);
            qf[s][kk] = u;
        }
    }
    float m[2][4], lsum[2][4];
    f32x4 acco[2][8];
#pragma unroll
    for (int s = 0; s < 2; ++s)
#pragma unroll
        for (int r = 0; r < 4; ++r) { m[s][r] = -1e30f; lsum[s][r] = 0.f; }
#pragma unroll
    for (int s = 0; s < 2; ++s)
#pragma unroll
        for (int n = 0; n < 8; ++n) acco[s][n] = (f32x4)0.f;

    const float* kb0 = K + b * (NHKV * HD) + hkv * HD;
    const float* vb0 = V + b * (NHKV * HD) + hkv * HD;

    for (int kvt = 0; kvt < SEQ / KVB; ++kvt) {
        const int kv0 = kvt * KVB;
        __syncthreads();
        const float* kb = kb0 + (size_t)kv0 * KSTRIDE;
#pragma unroll
        for (int i = 0; i < 2; ++i) {
            int c = i * 512 + tid;
            int row = c >> 4, c8 = c & 15;
            const float* src = kb + (size_t)row * KSTRIDE + c8 * 8;
            float4 f0 = *(const float4*)(src);
            float4 f1 = *(const float4*)(src + 4);
            ushort8 u;
            u[0] = f2bf(f0.x); u[1] = f2bf(f0.y); u[2] = f2bf(f0.z); u[3] = f2bf(f0.w);
            u[4] = f2bf(f1.x); u[5] = f2bf(f1.y); u[6] = f2bf(f1.z); u[7] = f2bf(f1.w);
            *(ushort8*)&kbuf[row * KPAD + c8 * 8] = u;
        }
        const float* vb = vb0 + (size_t)kv0 * KSTRIDE;
#pragma unroll
        for (int i = 0; i < 4; ++i) {
            int f4i = i * 512 + tid;
            int kv = f4i >> 5, d0 = (f4i & 31) * 4;
            float4 v4 = *(const float4*)(vb + (size_t)kv * KSTRIDE + d0);
            vbuf[(d0 + 0) * VPAD + kv] = f2bf(v4.x);
            vbuf[(d0 + 1) * VPAD + kv] = f2bf(v4.y);
            vbuf[(d0 + 2) * VPAD + kv] = f2bf(v4.z);
            vbuf[(d0 + 3) * VPAD + kv] = f2bf(v4.w);
        }
        __syncthreads();

        f32x4 sa[2][4];
#pragma unroll
        for (int s = 0; s < 2; ++s)
#pragma unroll
            for (int n = 0; n < 4; ++n) sa[s][n] = (f32x4)0.f;
#pragma unroll
        for (int kk = 0; kk < 4; ++kk) {
#pragma unroll
            for (int n = 0; n < 4; ++n) {
                bf16x8 bfr = *(const bf16x8*)&kbuf[(n * 16 + row16) * KPAD + kk * 32 + kg * 8];
                sa[0][n] = __builtin_amdgcn_mfma_f32_16x16x32_bf16(
                    __builtin_bit_cast(bf16x8, qf[0][kk]), bfr, sa[0][n], 0, 0, 0);
                sa[1][n] = __builtin_amdgcn_mfma_f32_16x16x32_bf16(
                    __builtin_bit_cast(bf16x8, qf[1][kk]), bfr, sa[1][n], 0, 0, 0);
            }
        }
#pragma unroll
        for (int s = 0; s < 2; ++s) {
#pragma unroll
            for (int r = 0; r < 4; ++r) {
                float tm = fmaxf(fmaxf(sa[s][0][r], sa[s][1][r]), fmaxf(sa[s][2][r], sa[s][3][r]));
                tm = fmaxf(tm, __shfl_xor(tm, 1, 16));
                tm = fmaxf(tm, __shfl_xor(tm, 2, 16));
                tm = fmaxf(tm, __shfl_xor(tm, 4, 16));
                tm = fmaxf(tm, __shfl_xor(tm, 8, 16));
                float mn = fmaxf(m[s][r], tm);
                float corr = __expf(m[s][r] - mn);
                float ps = 0.f;
                int prow = kg * 4 + r;
#pragma unroll
                for (int n = 0; n < 4; ++n) {
                    float p = __expf(sa[s][n][r] - mn);
                    ps += p;
                    pbuf[w][prow * PPAD + n * 16 + row16] = f2bf(p);
                }
                ps += __shfl_xor(ps, 1, 16);
                ps += __shfl_xor(ps, 2, 16);
                ps += __shfl_xor(ps, 4, 16);
                ps += __shfl_xor(ps, 8, 16);
                lsum[s][r] = lsum[s][r] * corr + ps;
                m[s][r] = mn;
#pragma unroll
                for (int n8 = 0; n8 < 8; ++n8) acco[s][n8][r] *= corr;
            }
#pragma unroll
            for (int kk2 = 0; kk2 < 2; ++kk2) {
                bf16x8 pa = *(const bf16x8*)&pbuf[w][row16 * PPAD + kk2 * 32 + kg * 8];
#pragma unroll
                for (int n8 = 0; n8 < 8; ++n8) {
                    bf16x8 vf = *(const bf16x8*)&vbuf[(n8 * 16 + row16) * VPAD + kk2 * 32 + kg * 8];
                    acco[s][n8] = __builtin_amdgcn_mfma_f32_16x16x32_bf16(pa, vf, acco[s][n8], 0, 0, 0);
                }
            }
        }
    }
    float* ob = O + b * (NHQ * HD) + hq * HD;
#pragma unroll
    for (int s = 0; s < 2; ++s)
#pragma unroll
        for (int r = 0; r < 4; ++r) {
            float inv = 1.f / lsum[s][r];
            int qrow = qbase + s * 16 + kg * 4 + r;
            float* op = ob + (size_t)qrow * QSTRIDE;
#pragma unroll
            for (int n8 = 0; n8 < 8; ++n8)
                op[n8 * 16 + row16] = acco[s][n8][r] * inv;
        }
}

extern "C" void kernel_launch(void* const* d_in, const int* in_sizes, int n_in,
                              void* d_out, int out_size, void* d_ws, size_t ws_size,
                              hipStream_t stream) {
    (void)in_sizes; (void)n_in; (void)out_size;
    const float* Q = (const float*)d_in[0];
    const float* K = (const float*)d_in[1];
    const float* V = (const float*)d_in[2];
    float* Out = (float*)d_out;

    const size_t kv_elems = (size_t)16 * 2048 * 128;      // per tensor (shorts)
    const size_t need = kv_elems * 2 * sizeof(unsigned short);  // 16.8 MB

    if (ws_size >= need) {
        unsigned short* Kws = (unsigned short*)d_ws;
        unsigned short* Vt  = Kws + kv_elems;
        conv_k<<<dim3(2048), dim3(256), 0, stream>>>(K, Kws);
        conv_v<<<dim3(512), dim3(256), 0, stream>>>(V, Vt);
        attn_fwd2<<<dim3(512), dim3(512), 0, stream>>>(Q, Kws, Vt, Out);
    } else {
        attn_fwd<<<dim3(512), dim3(512), 0, stream>>>(Q, K, V, Out);
    }
}

// Round 4
// 170.552 us; speedup vs baseline: 2.7161x; 1.5808x over previous
//
#include <hip/hip_runtime.h>

// Shapes (fixed)
#define SEQ   2048
#define NB    2
#define NHQ   32
#define NHKV  8
#define HD    128
#define QTILE 256
#define QW    32       // q rows per wave
#define KVB   64
#define NWAVE 8
#define SCALE 0.08838834764831845f
#define QSCALE (0.08838834764831845f * 1.4426950408889634f)   // fold log2(e): use exp2
#define THRL2 11.5f    // defer-max threshold (~8 nats) in log2 domain

#define QSTRIDE (NB * NHQ * HD)    // 8192
#define KSTRIDE (NB * NHKV * HD)   // 2048

typedef float f32x4  __attribute__((ext_vector_type(4)));
typedef float f32x16 __attribute__((ext_vector_type(16)));
typedef __bf16 bf16x8 __attribute__((ext_vector_type(8)));
typedef unsigned short ushort8 __attribute__((ext_vector_type(8)));
typedef unsigned int u32;
typedef unsigned int u32x2 __attribute__((ext_vector_type(2)));
typedef unsigned int u32x4 __attribute__((ext_vector_type(4)));

__device__ __forceinline__ unsigned short f2bf(float f) {
    union { float f; unsigned u; } c; c.f = f;
    return (unsigned short)((c.u + 0x7fffu + ((c.u >> 16) & 1u)) >> 16);
}

__device__ __forceinline__ void gload_lds16(const unsigned short* g, unsigned short* l) {
    __builtin_amdgcn_global_load_lds((const __attribute__((address_space(1))) u32*)g,
                                     (__attribute__((address_space(3))) u32*)l, 16, 0, 0);
}

__device__ __forceinline__ float ex2(float x) {
#if __has_builtin(__builtin_amdgcn_exp2f)
    return __builtin_amdgcn_exp2f(x);
#else
    return exp2f(x);
#endif
}

__device__ __forceinline__ u32 cvtpk(float lo, float hi) {
    u32 r;
    asm("v_cvt_pk_bf16_f32 %0, %1, %2" : "=v"(r) : "v"(lo), "v"(hi));
    return r;
}

// v_permlane32_swap_b32 a, b : swaps a's UPPER 32 lanes with b's LOWER 32 lanes
__device__ __forceinline__ void pl32swap(u32& a, u32& b) {
#if __has_builtin(__builtin_amdgcn_permlane32_swap)
    u32x2 r = __builtin_amdgcn_permlane32_swap(a, b, false, false);
    a = r.x; b = r.y;
#else
    asm("v_permlane32_swap_b32 %0, %1" : "+v"(a), "+v"(b));
#endif
}

// Build one PV B-fragment pair worth of words from 8 f32 P values (C-layout
// order crow = (r&3)+8*(r>>2)+4h). FIRST swap operand must be the LOW-kv pack:
// pl32swap(w0=pack(P[B+0..1]), w2=pack(P[B+4..5])) -> w0={h0:P[B+0,1]; h1:P[B+8,9]},
// w2={h0:P[B+4,5]; h1:P[B+12,13]}  (needed pa[j] = P[16ks+8h+j]).
template <int B>
__device__ __forceinline__ bf16x8 make_pa(const f32x16 p) {
    u32 w0 = cvtpk(p[B + 0], p[B + 1]);
    u32 w2 = cvtpk(p[B + 4], p[B + 5]);
    pl32swap(w0, w2);
    u32 w1 = cvtpk(p[B + 2], p[B + 3]);
    u32 w3 = cvtpk(p[B + 6], p[B + 7]);
    pl32swap(w1, w3);
    u32x4 v = {w0, w1, w2, w3};
    return __builtin_bit_cast(bf16x8, v);
}

// ---------------- pre-pass 1: K -> bf16, XOR-swizzled 16B chunks ----------------
__global__ __launch_bounds__(256) void conv_k(const float* __restrict__ K,
                                              unsigned short* __restrict__ Kws) {
    int idx = blockIdx.x * 256 + threadIdx.x;
    int c  = idx & 15;
    int s  = (idx >> 4) & 2047;
    int bh = idx >> 15;
    int cs = c ^ (s & 7);
    const float* src = K + ((size_t)s * 16 + bh) * 128 + cs * 8;
    float4 f0 = *(const float4*)src;
    float4 f1 = *(const float4*)(src + 4);
    ushort8 u;
    u[0] = f2bf(f0.x); u[1] = f2bf(f0.y); u[2] = f2bf(f0.z); u[3] = f2bf(f0.w);
    u[4] = f2bf(f1.x); u[5] = f2bf(f1.y); u[6] = f2bf(f1.z); u[7] = f2bf(f1.w);
    *(ushort8*)&Kws[((size_t)bh * 2048 + s) * 128 + c * 8] = u;
}

// ---------------- pre-pass 2: V -> bf16 transposed [bh][d][seq], swizzled ----------------
__global__ __launch_bounds__(256) void conv_v(const float* __restrict__ V,
                                              unsigned short* __restrict__ Vt) {
    __shared__ float tile[64][129];
    int t64 = blockIdx.x & 31;
    int bh  = blockIdx.x >> 5;
    int kv0 = t64 * 64;
#pragma unroll
    for (int i = 0; i < 8; ++i) {
        int f4 = i * 256 + threadIdx.x;
        int kv = f4 >> 5, d4 = (f4 & 31) * 4;
        float4 v = *(const float4*)(V + ((size_t)(kv0 + kv) * 16 + bh) * 128 + d4);
        tile[kv][d4] = v.x; tile[kv][d4 + 1] = v.y;
        tile[kv][d4 + 2] = v.z; tile[kv][d4 + 3] = v.w;
    }
    __syncthreads();
#pragma unroll
    for (int i = 0; i < 4; ++i) {
        int lin = i * 256 + threadIdx.x;
        int c = lin & 7, d = lin >> 3;
        int cs = c ^ (d & 7);
        ushort8 u;
#pragma unroll
        for (int j = 0; j < 8; ++j) u[j] = f2bf(tile[cs * 8 + j][d]);
        *(ushort8*)&Vt[((size_t)bh * 128 + d) * 2048 + kv0 + c * 8] = u;
    }
}

// ---------------- main attention kernel: 8 waves x 32q, 32x32 MFMA, swapped QK^T ----------------
__global__ __launch_bounds__(512, 2)
void attn_fwd3(const float* __restrict__ Q, const unsigned short* __restrict__ Kws,
               const unsigned short* __restrict__ Vtws, float* __restrict__ O) {
    // [0,16384) kbuf0 | [16384,32768) kbuf1 | [32768,49152) vbuf0 | [49152,65536) vbuf1
    // epilogue reuses bytes [0, 69632): 8 waves x 32x68 f32
    __shared__ __align__(16) unsigned char smemc[69632];

    const int tid  = threadIdx.x;
    const int w    = tid >> 6;
    const int lane = tid & 63;
    const int q31  = lane & 31;
    const int h    = lane >> 5;
    const int c7   = q31 & 7;

    const int bid   = blockIdx.x;
    const int qtile = bid & 7;
    const int g     = (bid >> 3) & 3;
    const int b     = (bid >> 5) & 1;
    const int hkv   = bid >> 6;
    const int hq    = hkv * 4 + g;

    const int qrow = qtile * QTILE + w * QW + q31;

    // ---- Q B-fragments: qf[s] elem j = Q[qrow][16s+8h+j] * QSCALE ----
    bf16x8 qf[8];
    {
        const float* qp = Q + (size_t)qrow * QSTRIDE + b * (NHQ * HD) + hq * HD;
#pragma unroll
        for (int s = 0; s < 8; ++s) {
            const float* p = qp + (2 * s + h) * 8;
            float4 f0 = *(const float4*)(p);
            float4 f1 = *(const float4*)(p + 4);
            ushort8 u;
            u[0] = f2bf(f0.x * QSCALE); u[1] = f2bf(f0.y * QSCALE);
            u[2] = f2bf(f0.z * QSCALE); u[3] = f2bf(f0.w * QSCALE);
            u[4] = f2bf(f1.x * QSCALE); u[5] = f2bf(f1.y * QSCALE);
            u[6] = f2bf(f1.z * QSCALE); u[7] = f2bf(f1.w * QSCALE);
            qf[s] = __builtin_bit_cast(bf16x8, u);
        }
    }

    // ---- precomputed per-lane LDS byte addresses (buffer 0), XOR-toggled per tile ----
    u32 kad[8], vad[4];
#pragma unroll
    for (int s = 0; s < 8; ++s)
        kad[s] = q31 * 256 + (((2 * s + h) ^ c7) << 4);
#pragma unroll
    for (int ks = 0; ks < 4; ++ks)
        vad[ks] = 32768 + q31 * 128 + (((2 * ks + h) ^ c7) << 4);

    f32x16 acc[4];
#pragma unroll
    for (int db = 0; db < 4; ++db) acc[db] = (f32x16)0.f;
    float mr = -3e38f, lsum = 0.f;

    const unsigned short* kbh = Kws  + (size_t)(b * 8 + hkv) * 2048 * 128;
    const unsigned short* vbh = Vtws + (size_t)(b * 8 + hkv) * 128 * 2048;

#define STAGE(bufi, tt) do {                                                           \
        const int kv0s = (tt) * KVB;                                                   \
        _Pragma("unroll")                                                              \
        for (int i_ = 0; i_ < 2; ++i_) {                                               \
            const int c_ = w * 2 + i_;                                                 \
            gload_lds16(kbh + (size_t)(kv0s + c_ * 4 + (lane >> 4)) * 128 + (lane & 15) * 8, \
                        (unsigned short*)(smemc + (bufi) * 16384 + c_ * 1024));        \
            gload_lds16(vbh + (size_t)(c_ * 8 + (lane >> 3)) * 2048 + kv0s + (lane & 7) * 8, \
                        (unsigned short*)(smemc + 32768 + (bufi) * 16384 + c_ * 1024)); \
        }                                                                              \
    } while (0)

    STAGE(0, 0);

    for (int t = 0; t < SEQ / KVB; ++t) {
        __syncthreads();
        if (t + 1 < SEQ / KVB) STAGE((t + 1) & 1, t + 1);

        // ---- S^T = K * Q : sa0 = kv[0..31], sa1 = kv[32..63]; lane col = own q ----
        f32x16 sa0 = (f32x16)0.f, sa1 = (f32x16)0.f;
#pragma unroll
        for (int s = 0; s < 8; ++s) {
            bf16x8 k0 = *(const bf16x8*)&smemc[kad[s]];
            bf16x8 k1 = *(const bf16x8*)&smemc[kad[s] + 8192];
            sa0 = __builtin_amdgcn_mfma_f32_32x32x16_bf16(k0, qf[s], sa0, 0, 0, 0);
            sa1 = __builtin_amdgcn_mfma_f32_32x32x16_bf16(k1, qf[s], sa1, 0, 0, 0);
        }

        // ---- in-register online softmax (log2 domain) ----
        float m4[4];
#pragma unroll
        for (int r = 0; r < 4; ++r)
            m4[r] = fmaxf(fmaxf(fmaxf(sa0[r], sa0[r + 4]), fmaxf(sa0[r + 8], sa0[r + 12])),
                          fmaxf(fmaxf(sa1[r], sa1[r + 4]), fmaxf(sa1[r + 8], sa1[r + 12])));
        float tm = fmaxf(fmaxf(m4[0], m4[1]), fmaxf(m4[2], m4[3]));
        tm = fmaxf(tm, __shfl_xor(tm, 32));

        if (!__all(tm <= mr + THRL2)) {           // defer-max (T13)
            float mn   = fmaxf(mr, tm);
            float corr = ex2(mr - mn);
            lsum *= corr;
#pragma unroll
            for (int db = 0; db < 4; ++db)
#pragma unroll
                for (int r = 0; r < 16; ++r) acc[db][r] *= corr;
            mr = mn;
        }

#pragma unroll
        for (int r = 0; r < 16; ++r) sa0[r] = ex2(sa0[r] - mr);
#pragma unroll
        for (int r = 0; r < 16; ++r) sa1[r] = ex2(sa1[r] - mr);
        float s4[4];
#pragma unroll
        for (int r = 0; r < 4; ++r)
            s4[r] = (sa0[r] + sa0[r + 4]) + (sa0[r + 8] + sa0[r + 12]) +
                    (sa1[r] + sa1[r + 4]) + (sa1[r + 8] + sa1[r + 12]);
        float ps = (s4[0] + s4[1]) + (s4[2] + s4[3]);
        ps += __shfl_xor(ps, 32);
        lsum += ps;

        // ---- P -> bf16 PV fragments (cvt_pk + permlane32_swap) ----
        bf16x8 pa[4];
        pa[0] = make_pa<0>(sa0);
        pa[1] = make_pa<8>(sa0);
        pa[2] = make_pa<0>(sa1);
        pa[3] = make_pa<8>(sa1);

        // ---- O^T += V^T * P^T : acc[db] col = own q, rows = d ----
#pragma unroll
        for (int db = 0; db < 4; ++db) {
#pragma unroll
            for (int ks = 0; ks < 4; ++ks) {
                bf16x8 vf = *(const bf16x8*)&smemc[vad[ks] + db * 4096];
                acc[db] = __builtin_amdgcn_mfma_f32_32x32x16_bf16(vf, pa[ks], acc[db], 0, 0, 0);
            }
        }

#pragma unroll
        for (int s = 0; s < 8; ++s) kad[s] ^= 16384;
#pragma unroll
        for (int ks = 0; ks < 4; ++ks) vad[ks] ^= 16384;
    }
#undef STAGE

    // ---- epilogue: normalize in-lane, transpose via LDS, coalesced float4 stores ----
    __syncthreads();   // everyone done reading K/V LDS
    float invl = 1.f / lsum;
    float* ep = (float*)(void*)smemc + w * 2176;   // 32 x 68 f32 per wave
    const int qtb = qtile * QTILE + w * QW;
    float* ob = O + b * (NHQ * HD) + hq * HD;

#pragma unroll
    for (int pass = 0; pass < 2; ++pass) {
#pragma unroll
        for (int db2 = 0; db2 < 2; ++db2) {
            const int db = pass * 2 + db2;
#pragma unroll
            for (int r = 0; r < 16; ++r)
                ep[q31 * 68 + db2 * 32 + (r & 3) + 8 * (r >> 2) + 4 * h] = acc[db][r] * invl;
        }
        __syncthreads();
#pragma unroll
        for (int i = 0; i < 8; ++i) {
            const int row = i * 4 + (lane >> 4);
            const int f4  = lane & 15;
            float4 val = *(const float4*)&ep[row * 68 + f4 * 4];
            *(float4*)(ob + (size_t)(qtb + row) * QSTRIDE + pass * 64 + f4 * 4) = val;
        }
        __syncthreads();
    }
}

// ---------------- fallback (round-1 kernel, used if ws too small) ----------------
#define KPAD  136
#define VPAD  72
#define PPAD  72
__global__ __launch_bounds__(512, 2)
void attn_fwd(const float* __restrict__ Q, const float* __restrict__ K,
              const float* __restrict__ V, float* __restrict__ O) {
    __shared__ __align__(16) unsigned short kbuf[KVB * KPAD];
    __shared__ __align__(16) unsigned short vbuf[HD * VPAD];
    __shared__ __align__(16) unsigned short pbuf[NWAVE][16 * PPAD];

    const int tid = threadIdx.x;
    const int w = tid >> 6, lane = tid & 63;
    const int row16 = lane & 15, kg = lane >> 4;
    const int bid = blockIdx.x;
    const int qtile = bid & 7, g = (bid >> 3) & 3, b = (bid >> 5) & 1, hkv = bid >> 6;
    const int hq = hkv * 4 + g;
    const int qbase = qtile * QTILE + w * 32;

    ushort8 qf[2][4];
#pragma unroll
    for (int s = 0; s < 2; ++s) {
        const int qrow = qbase + s * 16 + row16;
        const float* qp = Q + (size_t)qrow * QSTRIDE + b * (NHQ * HD) + hq * HD;
#pragma unroll
        for (int kk = 0; kk < 4; ++kk) {
            const float* p = qp + kk * 32 + kg * 8;
            float4 f0 = *(const float4*)(p);
            float4 f1 = *(const float4*)(p + 4);
            ushort8 u;
            u[0] = f2bf(f0.x * SCALE); u[1] = f2bf(f0.y * SCALE);
            u[2] = f2bf(f0.z * SCALE); u[3] = f2bf(f0.w * SCALE);
            u[4] = f2bf(f1.x * SCALE); u[5] = f2bf(f1.y * SCALE);
            u[6] = f2bf(f1.z * SCALE); u[7] = f2bf(f1.w * SCALE);
            qf[s][kk] = u;
        }
    }
    float m[2][4], lsum[2][4];
    f32x4 acco[2][8];
#pragma unroll
    for (int s = 0; s < 2; ++s)
#pragma unroll
        for (int r = 0; r < 4; ++r) { m[s][r] = -1e30f; lsum[s][r] = 0.f; }
#pragma unroll
    for (int s = 0; s < 2; ++s)
#pragma unroll
        for (int n = 0; n < 8; ++n) acco[s][n] = (f32x4)0.f;

    const float* kb0 = K + b * (NHKV * HD) + hkv * HD;
    const float* vb0 = V + b * (NHKV * HD) + hkv * HD;

    for (int kvt = 0; kvt < SEQ / KVB; ++kvt) {
        const int kv0 = kvt * KVB;
        __syncthreads();
        const float* kb = kb0 + (size_t)kv0 * KSTRIDE;
#pragma unroll
        for (int i = 0; i < 2; ++i) {
            int c = i * 512 + tid;
            int row = c >> 4, c8 = c & 15;
            const float* src = kb + (size_t)row * KSTRIDE + c8 * 8;
            float4 f0 = *(const float4*)(src);
            float4 f1 = *(const float4*)(src + 4);
            ushort8 u;
            u[0] = f2bf(f0.x); u[1] = f2bf(f0.y); u[2] = f2bf(f0.z); u[3] = f2bf(f0.w);
            u[4] = f2bf(f1.x); u[5] = f2bf(f1.y); u[6] = f2bf(f1.z); u[7] = f2bf(f1.w);
            *(ushort8*)&kbuf[row * KPAD + c8 * 8] = u;
        }
        const float* vb = vb0 + (size_t)kv0 * KSTRIDE;
#pragma unroll
        for (int i = 0; i < 4; ++i) {
            int f4i = i * 512 + tid;
            int kv = f4i >> 5, d0 = (f4i & 31) * 4;
            float4 v4 = *(const float4*)(vb + (size_t)kv * KSTRIDE + d0);
            vbuf[(d0 + 0) * VPAD + kv] = f2bf(v4.x);
            vbuf[(d0 + 1) * VPAD + kv] = f2bf(v4.y);
            vbuf[(d0 + 2) * VPAD + kv] = f2bf(v4.z);
            vbuf[(d0 + 3) * VPAD + kv] = f2bf(v4.w);
        }
        __syncthreads();

        f32x4 sa[2][4];
#pragma unroll
        for (int s = 0; s < 2; ++s)
#pragma unroll
            for (int n = 0; n < 4; ++n) sa[s][n] = (f32x4)0.f;
#pragma unroll
        for (int kk = 0; kk < 4; ++kk) {
#pragma unroll
            for (int n = 0; n < 4; ++n) {
                bf16x8 bfr = *(const bf16x8*)&kbuf[(n * 16 + row16) * KPAD + kk * 32 + kg * 8];
                sa[0][n] = __builtin_amdgcn_mfma_f32_16x16x32_bf16(
                    __builtin_bit_cast(bf16x8, qf[0][kk]), bfr, sa[0][n], 0, 0, 0);
                sa[1][n] = __builtin_amdgcn_mfma_f32_16x16x32_bf16(
                    __builtin_bit_cast(bf16x8, qf[1][kk]), bfr, sa[1][n], 0, 0, 0);
            }
        }
#pragma unroll
        for (int s = 0; s < 2; ++s) {
#pragma unroll
            for (int r = 0; r < 4; ++r) {
                float tm = fmaxf(fmaxf(sa[s][0][r], sa[s][1][r]), fmaxf(sa[s][2][r], sa[s][3][r]));
                tm = fmaxf(tm, __shfl_xor(tm, 1, 16));
                tm = fmaxf(tm, __shfl_xor(tm, 2, 16));
                tm = fmaxf(tm, __shfl_xor(tm, 4, 16));
                tm = fmaxf(tm, __shfl_xor(tm, 8, 16));
                float mn = fmaxf(m[s][r], tm);
                float corr = __expf(m[s][r] - mn);
                float ps = 0.f;
                int prow = kg * 4 + r;
#pragma unroll
                for (int n = 0; n < 4; ++n) {
                    float p = __expf(sa[s][n][r] - mn);
                    ps += p;
                    pbuf[w][prow * PPAD + n * 16 + row16] = f2bf(p);
                }
                ps += __shfl_xor(ps, 1, 16);
                ps += __shfl_xor(ps, 2, 16);
                ps += __shfl_xor(ps, 4, 16);
                ps += __shfl_xor(ps, 8, 16);
                lsum[s][r] = lsum[s][r] * corr + ps;
                m[s][r] = mn;
#pragma unroll
                for (int n8 = 0; n8 < 8; ++n8) acco[s][n8][r] *= corr;
            }
#pragma unroll
            for (int kk2 = 0; kk2 < 2; ++kk2) {
                bf16x8 pa = *(const bf16x8*)&pbuf[w][row16 * PPAD + kk2 * 32 + kg * 8];
#pragma unroll
                for (int n8 = 0; n8 < 8; ++n8) {
                    bf16x8 vf = *(const bf16x8*)&vbuf[(n8 * 16 + row16) * VPAD + kk2 * 32 + kg * 8];
                    acco[s][n8] = __builtin_amdgcn_mfma_f32_16x16x32_bf16(pa, vf, acco[s][n8], 0, 0, 0);
                }
            }
        }
    }
    float* ob = O + b * (NHQ * HD) + hq * HD;
#pragma unroll
    for (int s = 0; s < 2; ++s)
#pragma unroll
        for (int r = 0; r < 4; ++r) {
            float inv = 1.f / lsum[s][r];
            int qrow = qbase + s * 16 + kg * 4 + r;
            float* op = ob + (size_t)qrow * QSTRIDE;
#pragma unroll
            for (int n8 = 0; n8 < 8; ++n8)
                op[n8 * 16 + row16] = acco[s][n8][r] * inv;
        }
}

extern "C" void kernel_launch(void* const* d_in, const int* in_sizes, int n_in,
                              void* d_out, int out_size, void* d_ws, size_t ws_size,
                              hipStream_t stream) {
    (void)in_sizes; (void)n_in; (void)out_size;
    const float* Q = (const float*)d_in[0];
    const float* K = (const float*)d_in[1];
    const float* V = (const float*)d_in[2];
    float* Out = (float*)d_out;

    const size_t kv_elems = (size_t)16 * 2048 * 128;
    const size_t need = kv_elems * 2 * sizeof(unsigned short);

    if (ws_size >= need) {
        unsigned short* Kws = (unsigned short*)d_ws;
        unsigned short* Vt  = Kws + kv_elems;
        conv_k<<<dim3(2048), dim3(256), 0, stream>>>(K, Kws);
        conv_v<<<dim3(512), dim3(256), 0, stream>>>(V, Vt);
        attn_fwd3<<<dim3(512), dim3(512), 0, stream>>>(Q, Kws, Vt, Out);
    } else {
        attn_fwd<<<dim3(512), dim3(512), 0, stream>>>(Q, K, V, Out);
    }
}